// Round 2
// baseline (237.148 us; speedup 1.0000x reference)
//
#include <hip/hip_runtime.h>

#define J 17
#define F 128
#define TB 16          // batches per block (= MFMA N dim now)
#define THREADS 512    // 8 waves; wave w owns column tile ct = w (16 g columns)

typedef __attribute__((ext_vector_type(4))) float f32x4;
typedef __attribute__((ext_vector_type(8))) short bf16x8;   // 8 bf16 in 4 VGPRs

// round-to-nearest-even f32 -> bf16
__device__ __forceinline__ unsigned short f2bf(float f) {
    unsigned u = __builtin_bit_cast(unsigned, f);
    u += 0x7fffu + ((u >> 16) & 1u);
    return (unsigned short)(u >> 16);
}

__device__ __forceinline__ f32x4 fma4(float a, f32x4 v, f32x4 c) {
#pragma unroll
    for (int r = 0; r < 4; ++r) c[r] = __builtin_fmaf(a, v[r], c[r]);
    return c;
}

// ws layout: f32[0..288] = A_off (diag zeroed); f32[289..305] = A_diag;
// byte 2048: WT bf16 [2][g=128][k=128]  (WT[mat][g][k] = bf16(W[mat][k][g]))
__global__ void prep(const float* __restrict__ W, const float* __restrict__ adj,
                     const float* __restrict__ adj2, float* __restrict__ wsA,
                     unsigned short* __restrict__ WT) {
    int t = blockIdx.x * 256 + threadIdx.x;
    for (int idx = t; idx < 2 * F * F; idx += 16 * 256) {
        int mat = idx >> 14;
        int rem = idx & 16383;
        int g = rem >> 7, k = rem & 127;
        WT[idx] = f2bf(W[mat * 16384 + k * F + g]);   // write coalesced over k
    }
    if (blockIdx.x == 0) {
        for (int idx = threadIdx.x; idx < J * J; idx += 256) {
            int i = idx / J, j = idx % J;
            float a = 0.5f * (adj[i*J+j] + adj2[i*J+j] + adj[j*J+i] + adj2[j*J+i]);
            wsA[idx] = (i == j) ? 0.0f : a;
            if (i == j) wsA[J * J + i] = a;
        }
    }
}

__global__ __launch_bounds__(THREADS, 4) void mgcn_kernel(
    const float* __restrict__ x, const float* __restrict__ Mw,
    const float* __restrict__ bias, const float* __restrict__ wsA,
    const unsigned short* __restrict__ WT, float* __restrict__ out) {

    // x tile bf16, byte = b*4352 + j*256 + k*2, XOR-swizzled by (b&7)<<4
    __shared__ __align__(16) unsigned char xs[TB * J * F * 2];   // 69632 B
    __shared__ __align__(16) float Ms[J * F];                    //  8704 B

    const int tid = threadIdx.x;
    const int b0  = blockIdx.x * TB;

    for (int idx = tid; idx < J * F / 4; idx += THREADS)
        ((float4*)Ms)[idx] = ((const float4*)Mw)[idx];

    // ---- stage x: coalesced float4 reads -> bf16 -> swizzled 8B LDS writes ----
    const float4* xg = (const float4*)(x + (size_t)b0 * (J * F));
#pragma unroll
    for (int it = 0; it < (TB * J * F / 4) / THREADS; ++it) {   // 17 iters
        int fi = it * THREADS + tid;
        float4 v = xg[fi];
        int b  = fi / (J * F / 4);          // /544
        int r  = fi - b * (J * F / 4);
        int j  = r >> 5;
        int k0 = (r & 31) * 4;
        unsigned byte = (unsigned)(b * (J * F * 2) + j * (F * 2) + k0 * 2);
        byte ^= (unsigned)((b & 7) << 4);
        ushort4 u;
        u.x = f2bf(v.x); u.y = f2bf(v.y); u.z = f2bf(v.z); u.w = f2bf(v.w);
        *(ushort4*)(xs + byte) = u;
    }

    const int wave = tid >> 6;            // column tile ct = wave, g band [16w,16w+16)
    const int lane = tid & 63;
    const int lrow = lane & 15;
    const int lq   = lane >> 4;
    const int grow = wave * 16 + lrow;    // A-frag (W^T) row = g
    const int gq   = wave * 16 + lq * 4;  // D reg-quad g base

    // W^T fragments (A-operand), resident all pass: WT[mat][grow][ks*32+lq*8 ..+8]
    bf16x8 wf0[4], wf1[4];
#pragma unroll
    for (int ks = 0; ks < 4; ++ks) {
        const unsigned short* p0 = WT + (size_t)grow * F + ks * 32 + lq * 8;
        wf0[ks] = __builtin_bit_cast(bf16x8, *(const uint4*)p0);
        wf1[ks] = __builtin_bit_cast(bf16x8, *(const uint4*)(p0 + F * F));
    }

    const f32x4 bias4 = *(const f32x4*)(bias + gq);
    f32x4 acc[J];
#pragma unroll
    for (int i = 0; i < J; ++i) acc[i] = bias4;

    __syncthreads();

    const float* __restrict__ Aoff  = wsA;
    const float* __restrict__ Adiag = wsA + J * J;
    const unsigned rbase = (unsigned)(lrow * (J * F * 2));
    const unsigned swz   = (unsigned)((lrow & 7) << 4);

#pragma unroll
    for (int j = 0; j < J; ++j) {
        f32x4 h0 = {0.f, 0.f, 0.f, 0.f};
        f32x4 h1 = {0.f, 0.f, 0.f, 0.f};
#pragma unroll
        for (int ks = 0; ks < 4; ++ks) {
            unsigned byte = (rbase + (unsigned)(j * (F * 2) + ks * 64 + lq * 16)) ^ swz;
            bf16x8 xf = __builtin_bit_cast(bf16x8, *(const uint4*)(xs + byte));
            // swapped operands: D[g][b], A = W^T frag, B = x frag
            h0 = __builtin_amdgcn_mfma_f32_16x16x32_bf16(wf0[ks], xf, h0, 0, 0, 0);
            h1 = __builtin_amdgcn_mfma_f32_16x16x32_bf16(wf1[ks], xf, h1, 0, 0, 0);
        }
        // per-lane g's are gq..gq+3 -> M enters as a reg-quad (broadcast LDS read)
        f32x4 mj = *(const f32x4*)&Ms[j * F + gq];
        f32x4 t0, mh1;
#pragma unroll
        for (int r = 0; r < 4; ++r) { t0[r] = mj[r] * h0[r]; mh1[r] = mj[r] * h1[r]; }
        acc[j] = fma4(Adiag[j], t0, acc[j]);
#pragma unroll
        for (int i = 0; i < J; ++i)
            acc[i] = fma4(Aoff[i * J + j], mh1, acc[i]);
    }

    // epilogue: lane holds out[b0+lrow, i, gq..gq+3] -> one dwordx4 per i
    float* ob = out + ((size_t)(b0 + lrow) * J) * F + gq;
#pragma unroll
    for (int i = 0; i < J; ++i)
        *(f32x4*)(ob + (size_t)i * F) = acc[i];
}

extern "C" void kernel_launch(void* const* d_in, const int* in_sizes, int n_in,
                              void* d_out, int out_size, void* d_ws, size_t ws_size,
                              hipStream_t stream) {
    const float* x    = (const float*)d_in[0];
    const float* W    = (const float*)d_in[1];
    const float* Mw   = (const float*)d_in[2];
    const float* adj  = (const float*)d_in[3];
    const float* adj2 = (const float*)d_in[4];
    const float* bias = (const float*)d_in[5];
    float* out = (float*)d_out;
    float* wsA = (float*)d_ws;
    unsigned short* WT = (unsigned short*)((char*)d_ws + 2048);

    int Btot = in_sizes[0] / (J * F);   // 16384
    prep<<<16, 256, 0, stream>>>(W, adj, adj2, wsA, WT);
    mgcn_kernel<<<Btot / TB, THREADS, 0, stream>>>(x, Mw, bias, wsA, WT, out);
}

// Round 3
// 86.859 us; speedup vs baseline: 2.7303x; 2.7303x over previous
//
#include <hip/hip_runtime.h>

#define J 17
#define F 128
#define TB 16          // batches per block (= MFMA N dim)
#define THREADS 512    // 8 waves; wave w owns g band [16w, 16w+16)

typedef __attribute__((ext_vector_type(4))) float f32x4;
typedef __attribute__((ext_vector_type(8))) short bf16x8;   // 8 bf16 in 4 VGPRs

// round-to-nearest-even f32 -> bf16
__device__ __forceinline__ unsigned short f2bf(float f) {
    unsigned u = __builtin_bit_cast(unsigned, f);
    u += 0x7fffu + ((u >> 16) & 1u);
    return (unsigned short)(u >> 16);
}

__device__ __forceinline__ f32x4 fma4(float a, f32x4 v, f32x4 c) {
#pragma unroll
    for (int r = 0; r < 4; ++r) c[r] = __builtin_fmaf(a, v[r], c[r]);
    return c;
}

// ws layout: f32[0..288] = A_off (diag zeroed); f32[289..305] = A_diag;
// byte 2048: WT bf16 [2][g=128][k=128]  (WT[mat][g][k] = bf16(W[mat][k][g]))
__global__ void prep(const float* __restrict__ W, const float* __restrict__ adj,
                     const float* __restrict__ adj2, float* __restrict__ wsA,
                     unsigned short* __restrict__ WT) {
    int t = blockIdx.x * 256 + threadIdx.x;
    for (int idx = t; idx < 2 * F * F; idx += 16 * 256) {
        int mat = idx >> 14;
        int rem = idx & 16383;
        int g = rem >> 7, k = rem & 127;
        WT[idx] = f2bf(W[mat * 16384 + k * F + g]);
    }
    if (blockIdx.x == 0) {
        for (int idx = threadIdx.x; idx < J * J; idx += 256) {
            int i = idx / J, j = idx % J;
            float a = 0.5f * (adj[i*J+j] + adj2[i*J+j] + adj[j*J+i] + adj2[j*J+i]);
            wsA[idx] = (i == j) ? 0.0f : a;
            if (i == j) wsA[J * J + i] = a;
        }
    }
}

__global__ __launch_bounds__(THREADS, 2) void mgcn_kernel(
    const float* __restrict__ x, const float* __restrict__ Mw,
    const float* __restrict__ bias, const float* __restrict__ wsA,
    const unsigned short* __restrict__ WT, float* __restrict__ out) {

    // x tile bf16: byte = b*4352 + j*256 + k*2, XOR-swizzled by (b&7)<<4.
    // Reused by the epilogue as an 8-batch f32 out tile (exactly 69632 B).
    __shared__ __align__(16) unsigned char xs[TB * J * F * 2];   // 69632 B
    __shared__ __align__(16) float Ms[J * F];                    //  8704 B

    const int tid = threadIdx.x;
    const int b0  = blockIdx.x * TB;

    for (int idx = tid; idx < J * F / 4; idx += THREADS)
        ((float4*)Ms)[idx] = ((const float4*)Mw)[idx];

    // ---- stage x: coalesced float4 reads -> bf16 -> swizzled 8B LDS writes ----
    const float4* xg = (const float4*)(x + (size_t)b0 * (J * F));
#pragma unroll
    for (int it = 0; it < (TB * J * F / 4) / THREADS; ++it) {   // 17 iters
        int fi = it * THREADS + tid;
        float4 v = xg[fi];
        int b  = fi / (J * F / 4);          // /544
        int r  = fi - b * (J * F / 4);
        int j  = r >> 5;
        int k0 = (r & 31) * 4;
        unsigned byte = (unsigned)(b * (J * F * 2) + j * (F * 2) + k0 * 2);
        byte ^= (unsigned)((b & 7) << 4);
        ushort4 u;
        u.x = f2bf(v.x); u.y = f2bf(v.y); u.z = f2bf(v.z); u.w = f2bf(v.w);
        *(ushort4*)(xs + byte) = u;
    }

    const int wave = tid >> 6;
    const int lane = tid & 63;
    const int lrow = lane & 15;           // MFMA 16-index: D col = batch
    const int lq   = lane >> 4;
    const int grow = wave * 16 + lrow;    // A-frag (W^T) row = g
    const int gq   = wave * 16 + lq * 4;  // D reg-quad g base

    const f32x4 bias4 = *(const f32x4*)(bias + gq);
    f32x4 acc[J];
#pragma unroll
    for (int i = 0; i < J; ++i) acc[i] = bias4;

    const float* __restrict__ Aoff  = wsA;
    const float* __restrict__ Adiag = wsA + J * J;
    const unsigned rbase = (unsigned)(lrow * (J * F * 2));
    const unsigned swz   = (unsigned)((lrow & 7) << 4);

    __syncthreads();

    // ---- pass A: diagonal path, only wf0 live ----
    {
        bf16x8 wf0[4];
#pragma unroll
        for (int ks = 0; ks < 4; ++ks)
            wf0[ks] = __builtin_bit_cast(bf16x8,
                *(const uint4*)(WT + (size_t)grow * F + ks * 32 + lq * 8));
#pragma unroll
        for (int j = 0; j < J; ++j) {
            f32x4 h0 = {0.f, 0.f, 0.f, 0.f};
#pragma unroll
            for (int ks = 0; ks < 4; ++ks) {
                unsigned byte = (rbase + (unsigned)(j * (F * 2) + ks * 64 + lq * 16)) ^ swz;
                bf16x8 xf = __builtin_bit_cast(bf16x8, *(const uint4*)(xs + byte));
                h0 = __builtin_amdgcn_mfma_f32_16x16x32_bf16(wf0[ks], xf, h0, 0, 0, 0);
            }
            f32x4 mj = *(const f32x4*)&Ms[j * F + gq];
            f32x4 t0;
#pragma unroll
            for (int r = 0; r < 4; ++r) t0[r] = mj[r] * h0[r];
            acc[j] = fma4(Adiag[j], t0, acc[j]);
        }
    }

    // ---- pass B: off-diagonal path, only wf1 live ----
    {
        bf16x8 wf1[4];
#pragma unroll
        for (int ks = 0; ks < 4; ++ks)
            wf1[ks] = __builtin_bit_cast(bf16x8,
                *(const uint4*)(WT + (size_t)(F * F) + (size_t)grow * F + ks * 32 + lq * 8));
#pragma unroll
        for (int j = 0; j < J; ++j) {
            f32x4 h1 = {0.f, 0.f, 0.f, 0.f};
#pragma unroll
            for (int ks = 0; ks < 4; ++ks) {
                unsigned byte = (rbase + (unsigned)(j * (F * 2) + ks * 64 + lq * 16)) ^ swz;
                bf16x8 xf = __builtin_bit_cast(bf16x8, *(const uint4*)(xs + byte));
                h1 = __builtin_amdgcn_mfma_f32_16x16x32_bf16(wf1[ks], xf, h1, 0, 0, 0);
            }
            f32x4 mj = *(const f32x4*)&Ms[j * F + gq];
            f32x4 mh1;
#pragma unroll
            for (int r = 0; r < 4; ++r) mh1[r] = mj[r] * h1[r];
#pragma unroll
            for (int i = 0; i < J; ++i)
                acc[i] = fma4(Aoff[i * J + j], mh1, acc[i]);
        }
    }

    // ---- epilogue: acc -> LDS (swizzled) -> fully-coalesced 128B-line stores ----
    // Lane holds out[b0+lrow, i, gq..gq+3]. Two rounds of 8 batches through xs.
#pragma unroll 1
    for (int r = 0; r < 2; ++r) {
        __syncthreads();                       // xs free (round 0) / prev copy done
        if ((lrow >> 3) == r) {
            const int bl = lrow & 7;
            const unsigned base = (unsigned)(bl * (J * F * 4) + gq * 4);
            const unsigned esw  = (unsigned)((bl & 3) << 5);
#pragma unroll
            for (int i = 0; i < J; ++i)
                *(f32x4*)(xs + ((base + (unsigned)(i * F * 4)) ^ esw)) = acc[i];
        }
        __syncthreads();
        const size_t gbase = ((size_t)b0 + r * 8) * (J * F);
        for (int f = tid; f < 8 * J * F / 4; f += THREADS) {   // 4352 float4
            unsigned byte = (unsigned)f * 16u;
            unsigned bl   = byte / (unsigned)(J * F * 4);      // /8704
            float4 v = *(const float4*)(xs + (byte ^ ((bl & 3) << 5)));
            *(float4*)(out + gbase + (size_t)f * 4) = v;
        }
    }
}

extern "C" void kernel_launch(void* const* d_in, const int* in_sizes, int n_in,
                              void* d_out, int out_size, void* d_ws, size_t ws_size,
                              hipStream_t stream) {
    const float* x    = (const float*)d_in[0];
    const float* W    = (const float*)d_in[1];
    const float* Mw   = (const float*)d_in[2];
    const float* adj  = (const float*)d_in[3];
    const float* adj2 = (const float*)d_in[4];
    const float* bias = (const float*)d_in[5];
    float* out = (float*)d_out;
    float* wsA = (float*)d_ws;
    unsigned short* WT = (unsigned short*)((char*)d_ws + 2048);

    int Btot = in_sizes[0] / (J * F);   // 16384
    prep<<<16, 256, 0, stream>>>(W, adj, adj2, wsA, WT);
    mgcn_kernel<<<Btot / TB, THREADS, 0, stream>>>(x, Mw, bias, wsA, WT, out);
}